// Round 1
// baseline (1907.138 us; speedup 1.0000x reference)
//
#include <hip/hip_runtime.h>
#include <hip/hip_bf16.h>
#include <stdint.h>

// TemporalDecoder: 2-layer LSTM (H=256) encoder (S=64) + decoder (10 steps) + heads.
// Strategy: bf16 MFMA cell GEMMs (fp32 accum, fp32 c-state), gate-interleaved
// packed weights so the LSTM cell update fuses into the GEMM epilogue.

#define H 256
#define SS 64
#define NN 100
#define BNROWS 1600     // B*N = 16*100
#define KD 512          // concat(x|h) K for cells
#define STEPS 10

typedef __bf16 bf16_t;
typedef __attribute__((ext_vector_type(8))) __bf16 bf16x8;
typedef __attribute__((ext_vector_type(4))) float f32x4;

__device__ __forceinline__ float sigm(float x) { return 1.0f / (1.0f + __expf(-x)); }
__device__ __forceinline__ float tanh_c(float x) {
    x = fminf(fmaxf(x, -15.0f), 15.0f);   // clamp: avoid inf/inf NaN
    float e = __expf(2.0f * x);
    return (e - 1.0f) / (e + 1.0f);
}

// ---------------------------------------------------------------------------
// prep: pack weights to bf16.
// Cell weights reordered: new row nr = 4*j + gate  <-  old row gate*256 + j,
// cols = [W_ih | W_hh] (K=512). bias = b_ih + b_hh (same reorder).
// Head layer-1 stacked: rows 0-127 cen_w1, 128-255 svd_w1, 256-511 lsvd_w1.
// ---------------------------------------------------------------------------
__global__ __launch_bounds__(256)
void prep_kernel(const float* __restrict__ Wih0, const float* __restrict__ Whh0,
                 const float* __restrict__ bih0, const float* __restrict__ bhh0,
                 const float* __restrict__ Wih1, const float* __restrict__ Whh1,
                 const float* __restrict__ bih1, const float* __restrict__ bhh1,
                 const float* __restrict__ cw1, const float* __restrict__ sw1,
                 const float* __restrict__ lw1,
                 const float* __restrict__ cb1, const float* __restrict__ sb1,
                 const float* __restrict__ lb1,
                 bf16_t* __restrict__ W0c, bf16_t* __restrict__ W1c,
                 bf16_t* __restrict__ Wh1, float* __restrict__ bias0,
                 float* __restrict__ bias1, float* __restrict__ biash)
{
    int idx = blockIdx.x * 256 + threadIdx.x;
    if (idx < 524288) {
        int nr = idx >> 9, k = idx & 511;
        int j = nr >> 2, gi = nr & 3;
        int go = gi * 256 + j;
        float v = (k < 256) ? Wih0[go * 256 + k] : Whh0[go * 256 + (k - 256)];
        W0c[idx] = (bf16_t)v;
        return;
    }
    idx -= 524288;
    if (idx < 524288) {
        int nr = idx >> 9, k = idx & 511;
        int j = nr >> 2, gi = nr & 3;
        int go = gi * 256 + j;
        float v = (k < 256) ? Wih1[go * 256 + k] : Whh1[go * 256 + (k - 256)];
        W1c[idx] = (bf16_t)v;
        return;
    }
    idx -= 524288;
    if (idx < 131072) {
        int r = idx >> 8, k = idx & 255;
        float v = (r < 128) ? cw1[r * 256 + k]
                            : (r < 256 ? sw1[(r - 128) * 256 + k]
                                       : lw1[(r - 256) * 256 + k]);
        Wh1[idx] = (bf16_t)v;
        return;
    }
    idx -= 131072;
    if (idx < 1024) {
        int j = idx >> 2, gi = idx & 3, go = gi * 256 + j;
        bias0[idx] = bih0[go] + bhh0[go];
        return;
    }
    idx -= 1024;
    if (idx < 1024) {
        int j = idx >> 2, gi = idx & 3, go = gi * 256 + j;
        bias1[idx] = bih1[go] + bhh1[go];
        return;
    }
    idx -= 1024;
    if (idx < 512) {
        biash[idx] = (idx < 128) ? cb1[idx]
                                 : (idx < 256 ? sb1[idx - 128] : lb1[idx - 256]);
    }
}

// ---------------------------------------------------------------------------
// Fused LSTM cell: gates = [A1|A2] @ Wc^T + bias (bf16 MFMA, fp32 accum),
// then c' = sig(f)*c + sig(i)*tanh(g); h' = sig(o)*tanh(c').
// Tile: BM=64 x BN=64 (new gate cols = 16 h-cols), BK=64, grid (25,16).
// A source: encoder layer0 reads fp32 x directly (converted in staging);
// otherwise bf16 h buffers. xsrc!=null selects x-mode.
// ---------------------------------------------------------------------------
__global__ __launch_bounds__(256)
void cell_kernel(const float* __restrict__ xsrc, int t,
                 const bf16_t* __restrict__ a1,
                 const bf16_t* __restrict__ a2,
                 const bf16_t* __restrict__ Wc,     // [1024][512] reordered
                 const float* __restrict__ biasr,   // [1024] reordered
                 float* __restrict__ cst,           // [1600][256] fp32, in-place
                 bf16_t* __restrict__ hout)         // [1600][256] bf16
{
    __shared__ char smem_raw[18432];
    bf16_t* As = (bf16_t*)smem_raw;                // [64][72] (pad 8 -> 2-way free)
    bf16_t* Bs = (bf16_t*)(smem_raw + 9216);       // [64][72]
    float*  Gs = (float*)smem_raw;                 // [64][68] epilogue overlay

    const int tid  = threadIdx.x;
    const int mblk = blockIdx.x;   // 0..24
    const int nblk = blockIdx.y;   // 0..15

    const int am = tid >> 2;              // 0..63 (A row; also B row)
    const int kc = (tid & 3) << 4;        // 0,16,32,48
    const int gm = mblk * 64 + am;

    const float*  xrow  = nullptr;
    const bf16_t* arow1 = nullptr;
    if (xsrc) {
        int b = gm / NN;
        int n = gm - b * NN;
        xrow = xsrc + (((size_t)b * SS + t) * NN + n) * H;
    } else {
        arow1 = a1 + (size_t)gm * H;
    }
    const bf16_t* arow2 = a2 + (size_t)gm * H;
    const bf16_t* brow  = Wc + (size_t)(nblk * 64 + am) * KD;

    bf16x8 ra0, ra1, rb0, rb1;

    auto loadA = [&](int ko) {
        int k = ko + kc;
        if (xsrc) {
            if (k < 256) {
                const f32x4* p = (const f32x4*)(xrow + k);
                f32x4 f0 = p[0], f1 = p[1], f2 = p[2], f3 = p[3];
                bf16x8 v0, v1;
                v0[0]=(bf16_t)f0.x; v0[1]=(bf16_t)f0.y; v0[2]=(bf16_t)f0.z; v0[3]=(bf16_t)f0.w;
                v0[4]=(bf16_t)f1.x; v0[5]=(bf16_t)f1.y; v0[6]=(bf16_t)f1.z; v0[7]=(bf16_t)f1.w;
                v1[0]=(bf16_t)f2.x; v1[1]=(bf16_t)f2.y; v1[2]=(bf16_t)f2.z; v1[3]=(bf16_t)f2.w;
                v1[4]=(bf16_t)f3.x; v1[5]=(bf16_t)f3.y; v1[6]=(bf16_t)f3.z; v1[7]=(bf16_t)f3.w;
                ra0 = v0; ra1 = v1;
            } else {
                const bf16x8* p = (const bf16x8*)(arow2 + (k - 256));
                ra0 = p[0]; ra1 = p[1];
            }
        } else {
            const bf16x8* p = (k < 256) ? (const bf16x8*)(arow1 + k)
                                        : (const bf16x8*)(arow2 + (k - 256));
            ra0 = p[0]; ra1 = p[1];
        }
    };
    auto loadB = [&](int ko) {
        const bf16x8* p = (const bf16x8*)(brow + ko + kc);
        rb0 = p[0]; rb1 = p[1];
    };

    loadA(0); loadB(0);

    const int w    = tid >> 6;
    const int lane = tid & 63;
    const int wm   = w & 1, wn = w >> 1;
    const int quad = lane >> 4, l16 = lane & 15;

    f32x4 zero4 = {0.f, 0.f, 0.f, 0.f};
    f32x4 acc[2][2] = {{zero4, zero4}, {zero4, zero4}};

    for (int kk = 0; kk < 8; ++kk) {
        __syncthreads();
        *(bf16x8*)(As + am * 72 + kc)     = ra0;
        *(bf16x8*)(As + am * 72 + kc + 8) = ra1;
        *(bf16x8*)(Bs + am * 72 + kc)     = rb0;
        *(bf16x8*)(Bs + am * 72 + kc + 8) = rb1;
        __syncthreads();
        if (kk < 7) { loadA((kk + 1) * 64); loadB((kk + 1) * 64); }  // prefetch
        #pragma unroll
        for (int ks = 0; ks < 2; ++ks) {
            bf16x8 af[2], bb[2];
            #pragma unroll
            for (int mi = 0; mi < 2; ++mi)
                af[mi] = *(const bf16x8*)(As + (wm * 32 + mi * 16 + l16) * 72 + ks * 32 + quad * 8);
            #pragma unroll
            for (int ni = 0; ni < 2; ++ni)
                bb[ni] = *(const bf16x8*)(Bs + (wn * 32 + ni * 16 + l16) * 72 + ks * 32 + quad * 8);
            #pragma unroll
            for (int mi = 0; mi < 2; ++mi)
                #pragma unroll
                for (int ni = 0; ni < 2; ++ni)
                    acc[mi][ni] = __builtin_amdgcn_mfma_f32_16x16x32_bf16(
                        af[mi], bb[ni], acc[mi][ni], 0, 0, 0);
        }
    }

    __syncthreads();   // all frag reads done before Gs overlay write
    float bv[2];
    #pragma unroll
    for (int ni = 0; ni < 2; ++ni)
        bv[ni] = biasr[nblk * 64 + wn * 32 + ni * 16 + l16];

    #pragma unroll
    for (int mi = 0; mi < 2; ++mi)
        #pragma unroll
        for (int ni = 0; ni < 2; ++ni)
            #pragma unroll
            for (int r = 0; r < 4; ++r) {
                int ml = wm * 32 + mi * 16 + quad * 4 + r;   // C row = quad*4+reg
                int nl = wn * 32 + ni * 16 + l16;            // C col = lane&15
                Gs[ml * 68 + nl] = acc[mi][ni][r] + bv[ni];
            }
    __syncthreads();

    // cell update: 64 rows x 16 h-cols per block, 4 per thread
    #pragma unroll
    for (int e = 0; e < 4; ++e) {
        int id = tid + 256 * e;
        int ml = id >> 4;
        int jl = id & 15;
        f32x4 g4 = *(const f32x4*)(Gs + ml * 68 + jl * 4);   // i,f,g,o
        int gmm = mblk * 64 + ml;
        int jg  = nblk * 16 + jl;
        float co = cst[(size_t)gmm * H + jg];
        float iv = sigm(g4.x);
        float fv = sigm(g4.y);
        float gv = tanh_c(g4.z);
        float ov = sigm(g4.w);
        float cn = fv * co + iv * gv;
        float hn = ov * tanh_c(cn);
        cst[(size_t)gmm * H + jg]  = cn;
        hout[(size_t)gmm * H + jg] = (bf16_t)hn;
    }
}

// ---------------------------------------------------------------------------
// heads layer 1: hid[1600][512] = relu(ht @ Wh1^T + biash), bf16 MFMA.
// Tile 64x64, K=256, grid (25,8).
// ---------------------------------------------------------------------------
__global__ __launch_bounds__(256)
void heads1_kernel(const bf16_t* __restrict__ a1,
                   const bf16_t* __restrict__ Wh,    // [512][256]
                   const float* __restrict__ biash,  // [512]
                   bf16_t* __restrict__ hid)         // [1600][512]
{
    __shared__ char smem_raw[18432];
    bf16_t* As = (bf16_t*)smem_raw;
    bf16_t* Bs = (bf16_t*)(smem_raw + 9216);

    const int tid  = threadIdx.x;
    const int mblk = blockIdx.x;   // 0..24
    const int nblk = blockIdx.y;   // 0..7

    const int am = tid >> 2;
    const int kc = (tid & 3) << 4;
    const int gm = mblk * 64 + am;
    const bf16_t* arow = a1 + (size_t)gm * H;
    const bf16_t* brow = Wh + (size_t)(nblk * 64 + am) * H;

    bf16x8 ra0, ra1, rb0, rb1;
    auto load = [&](int ko) {
        const bf16x8* pa = (const bf16x8*)(arow + ko + kc);
        ra0 = pa[0]; ra1 = pa[1];
        const bf16x8* pb = (const bf16x8*)(brow + ko + kc);
        rb0 = pb[0]; rb1 = pb[1];
    };
    load(0);

    const int w    = tid >> 6;
    const int lane = tid & 63;
    const int wm   = w & 1, wn = w >> 1;
    const int quad = lane >> 4, l16 = lane & 15;

    f32x4 zero4 = {0.f, 0.f, 0.f, 0.f};
    f32x4 acc[2][2] = {{zero4, zero4}, {zero4, zero4}};

    for (int kk = 0; kk < 4; ++kk) {
        __syncthreads();
        *(bf16x8*)(As + am * 72 + kc)     = ra0;
        *(bf16x8*)(As + am * 72 + kc + 8) = ra1;
        *(bf16x8*)(Bs + am * 72 + kc)     = rb0;
        *(bf16x8*)(Bs + am * 72 + kc + 8) = rb1;
        __syncthreads();
        if (kk < 3) load((kk + 1) * 64);
        #pragma unroll
        for (int ks = 0; ks < 2; ++ks) {
            bf16x8 af[2], bb[2];
            #pragma unroll
            for (int mi = 0; mi < 2; ++mi)
                af[mi] = *(const bf16x8*)(As + (wm * 32 + mi * 16 + l16) * 72 + ks * 32 + quad * 8);
            #pragma unroll
            for (int ni = 0; ni < 2; ++ni)
                bb[ni] = *(const bf16x8*)(Bs + (wn * 32 + ni * 16 + l16) * 72 + ks * 32 + quad * 8);
            #pragma unroll
            for (int mi = 0; mi < 2; ++mi)
                #pragma unroll
                for (int ni = 0; ni < 2; ++ni)
                    acc[mi][ni] = __builtin_amdgcn_mfma_f32_16x16x32_bf16(
                        af[mi], bb[ni], acc[mi][ni], 0, 0, 0);
        }
    }

    #pragma unroll
    for (int mi = 0; mi < 2; ++mi)
        #pragma unroll
        for (int ni = 0; ni < 2; ++ni)
            #pragma unroll
            for (int r = 0; r < 4; ++r) {
                int mg = mblk * 64 + wm * 32 + mi * 16 + quad * 4 + r;
                int ng = nblk * 64 + wn * 32 + ni * 16 + l16;
                float v = acc[mi][ni][r] + biash[ng];
                hid[(size_t)mg * 512 + ng] = (bf16_t)fmaxf(v, 0.0f);
            }
}

// ---------------------------------------------------------------------------
// heads layer 2: out[b][s][n][22]. thread = (sample, o). Block-diagonal:
// o<4: cen (k 0..127), o<6: svd (k 128..255), else lsvd (k 256..511).
// ---------------------------------------------------------------------------
__global__ __launch_bounds__(256)
void heads2_kernel(const bf16_t* __restrict__ hid,
                   const float* __restrict__ cw2, const float* __restrict__ cb2,
                   const float* __restrict__ sw2, const float* __restrict__ sb2,
                   const float* __restrict__ lw2, const float* __restrict__ lb2,
                   float* __restrict__ out, int s)
{
    int idx = blockIdx.x * 256 + threadIdx.x;
    if (idx >= BNROWS * 22) return;
    int m = idx / 22;
    int o = idx - m * 22;
    const bf16_t* hrow = hid + (size_t)m * 512;
    const float* wp; float bias; int k0, len;
    if (o < 4)      { wp = cw2 + o * 128;       bias = cb2[o];     k0 = 0;   len = 128; }
    else if (o < 6) { wp = sw2 + (o - 4) * 128; bias = sb2[o - 4]; k0 = 128; len = 128; }
    else            { wp = lw2 + (o - 6) * 256; bias = lb2[o - 6]; k0 = 256; len = 256; }
    float acc = bias;
    for (int k = 0; k < len; k += 4) {
        f32x4 wv = *(const f32x4*)(wp + k);
        acc += (float)hrow[k0 + k]     * wv.x;
        acc += (float)hrow[k0 + k + 1] * wv.y;
        acc += (float)hrow[k0 + k + 2] * wv.z;
        acc += (float)hrow[k0 + k + 3] * wv.w;
    }
    int b = m / NN, n = m - b * NN;
    out[(((size_t)b * STEPS + s) * NN + n) * 22 + o] = acc;
}

// ---------------------------------------------------------------------------
// LayerNorm over H=256: one wave per sample, 4 samples per block.
// ---------------------------------------------------------------------------
__global__ __launch_bounds__(256)
void ln_kernel(const bf16_t* __restrict__ hin,
               const float* __restrict__ gam, const float* __restrict__ bet,
               bf16_t* __restrict__ hto)
{
    int w = threadIdx.x >> 6;
    int lane = threadIdx.x & 63;
    int sample = blockIdx.x * 4 + w;
    const bf16_t* row = hin + (size_t)sample * H;
    float v[4];
    #pragma unroll
    for (int j = 0; j < 4; ++j) v[j] = (float)row[lane * 4 + j];
    float sm = v[0] + v[1] + v[2] + v[3];
    #pragma unroll
    for (int off = 32; off > 0; off >>= 1) sm += __shfl_xor(sm, off);
    float mean = sm * (1.0f / H);
    float q = 0.f;
    #pragma unroll
    for (int j = 0; j < 4; ++j) { float d = v[j] - mean; q += d * d; }
    #pragma unroll
    for (int off = 32; off > 0; off >>= 1) q += __shfl_xor(q, off);
    float rstd = rsqrtf(q * (1.0f / H) + 1e-5f);
    #pragma unroll
    for (int j = 0; j < 4; ++j) {
        int idx = lane * 4 + j;
        float o = (v[j] - mean) * rstd * gam[idx] + bet[idx];
        hto[(size_t)sample * H + idx] = (bf16_t)o;
    }
}

// ---------------------------------------------------------------------------
extern "C" void kernel_launch(void* const* d_in, const int* in_sizes, int n_in,
                              void* d_out, int out_size, void* d_ws, size_t ws_size,
                              hipStream_t stream)
{
    const float* x    = (const float*)d_in[0];
    const float* Wih0 = (const float*)d_in[1];
    const float* Whh0 = (const float*)d_in[2];
    const float* bih0 = (const float*)d_in[3];
    const float* bhh0 = (const float*)d_in[4];
    const float* Wih1 = (const float*)d_in[5];
    const float* Whh1 = (const float*)d_in[6];
    const float* bih1 = (const float*)d_in[7];
    const float* bhh1 = (const float*)d_in[8];
    const float* lng  = (const float*)d_in[9];
    const float* lnb  = (const float*)d_in[10];
    const float* cw1  = (const float*)d_in[11];
    const float* cb1  = (const float*)d_in[12];
    const float* cw2  = (const float*)d_in[13];
    const float* cb2  = (const float*)d_in[14];
    const float* sw1  = (const float*)d_in[15];
    const float* sb1  = (const float*)d_in[16];
    const float* sw2  = (const float*)d_in[17];
    const float* sb2  = (const float*)d_in[18];
    const float* lw1  = (const float*)d_in[19];
    const float* lb1  = (const float*)d_in[20];
    const float* lw2  = (const float*)d_in[21];
    const float* lb2  = (const float*)d_in[22];
    float* out = (float*)d_out;

    char* ws = (char*)d_ws;
    if (ws_size < 11500000) return;   // need ~11.4 MB scratch

    bf16_t* W0c   = (bf16_t*)(ws);             // 1,048,576 B
    bf16_t* W1c   = (bf16_t*)(ws + 1048576);   // 1,048,576
    bf16_t* Wh1w  = (bf16_t*)(ws + 2097152);   //   262,144
    float*  bias0 = (float*)(ws + 2359296);    //     4,096
    float*  bias1 = (float*)(ws + 2363392);    //     4,096
    float*  biash = (float*)(ws + 2367488);    //     2,048
    char* st = ws + 2369536;
    bf16_t* h0[2] = { (bf16_t*)st, (bf16_t*)(st + 819200) };
    bf16_t* h1[2] = { (bf16_t*)(st + 1638400), (bf16_t*)(st + 2457600) };
    float*  c0 = (float*)(st + 3276800);
    float*  c1 = (float*)(st + 4915200);
    bf16_t* ht  = (bf16_t*)(st + 6553600);
    bf16_t* hid = (bf16_t*)(st + 7372800);

    // zero h0[*], h1[*], c0, c1 (one contiguous region)
    hipMemsetAsync(st, 0, 6553600, stream);

    prep_kernel<<<4615, 256, 0, stream>>>(Wih0, Whh0, bih0, bhh0,
                                          Wih1, Whh1, bih1, bhh1,
                                          cw1, sw1, lw1, cb1, sb1, lb1,
                                          W0c, W1c, Wh1w, bias0, bias1, biash);

    dim3 cg(25, 16);
    int cur = 0;
    for (int t = 0; t < SS; ++t) {
        cell_kernel<<<cg, 256, 0, stream>>>(x, t, nullptr, h0[cur], W0c, bias0,
                                            c0, h0[cur ^ 1]);
        cell_kernel<<<cg, 256, 0, stream>>>(nullptr, 0, h0[cur ^ 1], h1[cur], W1c,
                                            bias1, c1, h1[cur ^ 1]);
        cur ^= 1;
    }
    ln_kernel<<<400, 256, 0, stream>>>(h1[cur], lng, lnb, ht);

    for (int s = 0; s < STEPS; ++s) {
        heads1_kernel<<<dim3(25, 8), 256, 0, stream>>>(ht, Wh1w, biash, hid);
        heads2_kernel<<<138, 256, 0, stream>>>(hid, cw2, cb2, sw2, sb2, lw2, lb2,
                                               out, s);
        cell_kernel<<<cg, 256, 0, stream>>>(nullptr, 0, ht, h0[cur], W0c, bias0,
                                            c0, h0[cur ^ 1]);
        cell_kernel<<<cg, 256, 0, stream>>>(nullptr, 0, h0[cur ^ 1], h1[cur], W1c,
                                            bias1, c1, h1[cur ^ 1]);
        cur ^= 1;
        ln_kernel<<<400, 256, 0, stream>>>(h1[cur], lng, lnb, ht);
    }
}